// Round 8
// baseline (380.727 us; speedup 1.0000x reference)
//
#include <hip/hip_runtime.h>
#include <hip/hip_bf16.h>
#include <math.h>

// Problem constants (from reference): B=2048, I=512, O=512
#define B_DIM 2048
#define I_DIM 512
#define O_DIM 512

constexpr int R_ROWS  = 8;   // b-rows per block -> grid 512 = 2 blocks/CU
constexpr int W_CHUNK = 4;   // i-chunks (threadIdx.y)
constexpr int N_ST    = 16;  // 8-i stages per chunk (128 i / 8)

// ws layout: abT [0, 2MB), xt [2MB, 6MB).
//   abT: float4 (a0,b0,a1,b1) at abT[o*256 + p], p = i/2 — per-o column is
//        4KB contiguous; chunk y starts at pair y*64; stage offsets are
//        immediates (<= 1008B).
//   xt : per (g,y,st) slab of 8 rows x 8 i = 64 floats = 256B contiguous:
//        xt[((g*4+y)*16+st)*64 + r*8 + e] = x[g*8+r][y*128+st*8+e]
//        -> one stage's x = 4 merged s_load_dwordx16.
#define ABT_OFFSET 0
#define XT_OFFSET ((size_t)2 * 1024 * 1024)

// ---------------------------------------------------------------------------
// Setup: blocks [0,512) build abT, blocks [512,1536) re-tile x.
//   factor[b,i,o] = a[i,o] + bcoef[i,o]*x[b,i];  a = 1-w*s, b = w*(2s-1)
// ---------------------------------------------------------------------------
__global__ __launch_bounds__(256) void setup_kernel(
    const float* __restrict__ x,
    const float* __restrict__ w_logits,
    const float* __restrict__ s_logits,
    float4* __restrict__ abT,
    float* __restrict__ xt)
{
    const int blk = blockIdx.x;
    if (blk < 512) {
        int t = blk * 256 + threadIdx.x;          // 0..131071
        int o = t & (O_DIM - 1);                  // lane-fast -> coalesced reads
        int p = t >> 9;                           // i-pair, 0..255
        int i0 = 2 * p;

        float zw0 = w_logits[(i0 + 0) * O_DIM + o];
        float zs0 = s_logits[(i0 + 0) * O_DIM + o];
        float zw1 = w_logits[(i0 + 1) * O_DIM + o];
        float zs1 = s_logits[(i0 + 1) * O_DIM + o];

        float w0 = 1.0f / (1.0f + expf(-zw0));
        float s0 = 1.0f / (1.0f + expf(-zs0));
        float w1 = 1.0f / (1.0f + expf(-zw1));
        float s1 = 1.0f / (1.0f + expf(-zs1));

        float4 v;
        v.x = fmaf(-w0, s0, 1.0f);        // a0
        v.y = w0 * (2.0f * s0 - 1.0f);    // b0
        v.z = fmaf(-w1, s1, 1.0f);        // a1
        v.w = w1 * (2.0f * s1 - 1.0f);    // b1
        abT[(size_t)o * 256 + p] = v;     // scattered 16B store (2MB total)
    } else {
        int t  = (blk - 512) * 256 + threadIdx.x; // 0..262143
        int iq = t & 127;                         // i-quad, lane-fast read
        int b  = t >> 7;
        float4 v = ((const float4*)x)[(size_t)b * 128 + iq];
        int g  = b >> 3, r = b & 7;
        int y  = iq >> 5, st = (iq >> 1) & 15, q = iq & 1;
        // slab-contiguous: float4 index = ((g*4+y)*16+st)*16 + r*2 + q
        ((float4*)xt)[(size_t)(((g * 4 + y) * 16 + st) * 16) + r * 2 + q] = v;
    }
}

// ---------------------------------------------------------------------------
// Main. Block (256,4) = 16 waves: lanes = o, y = i-chunk. Grid (2,256) =
// 512 blocks -> 2 blocks/CU, 32 waves/CU (8/SIMD).
// x feed stays on SMEM (the only datapath-efficient broadcast: 64B/instr to
// all lanes) but with an 8-i stage: one lgkmcnt(0) drain per 256 cyc of
// math. 8 waves/SIMD x 256 cyc >> drain (~450 cyc) -> issue-saturated.
// ab feed: lane-varying global_load_dwordx4 ping-pong (in-order vmcnt,
// prefetched 2 stages ahead, immediate offsets, no 64-bit math in loop).
// ---------------------------------------------------------------------------
__global__ __launch_bounds__(1024, 8) void fuzzy_main(
    const float4* __restrict__ abT,
    const float* __restrict__ xt,
    float* __restrict__ out)
{
    __shared__ float part[W_CHUNK][R_ROWS][256];   // 32 KB (2 blocks/CU)

    const int o_l = threadIdx.x;              // 0..255
    const int o   = blockIdx.x * 256 + o_l;
    const int y   = __builtin_amdgcn_readfirstlane((int)threadIdx.y); // 0..3
    const int g   = blockIdx.y;               // b-group (8 rows)
    const int b0  = g * R_ROWS;

    // ab column for this (o, y): pairs [y*64, y*64+64), stage st -> float4s
    // [4st, 4st+4): byte offsets 64*st..64*st+48 <= 1008, all immediates.
    const float4* __restrict__ abp = abT + (size_t)o * 256 + (size_t)y * 64;
    // x slabs for this (g, y): 16 stages x 64 floats, contiguous; uniform.
    const float*  __restrict__ xs  = xt + (size_t)(g * 4 + y) * 1024;

    float acc[R_ROWS];
#pragma unroll
    for (int r = 0; r < R_ROWS; ++r) acc[r] = 1.0f;

    // ab ping-pong: A = even stages, B = odd stages, depth 2 (no rotation).
    float4 cA0 = abp[0], cA1 = abp[1], cA2 = abp[2], cA3 = abp[3];
    float4 cB0 = abp[4], cB1 = abp[5], cB2 = abp[6], cB3 = abp[7];

    for (int st = 0; st < N_ST; st += 2) {
        // ---- stage A: i-block st (8 i), x slab xs[0..63] ----
        {
#pragma unroll
            for (int r = 0; r < R_ROWS; ++r) {
                const float* xr = xs + r * 8;     // uniform -> s_load (merged x16)
                float f0 = fmaf(cA0.y, xr[0], cA0.x);
                float f1 = fmaf(cA0.w, xr[1], cA0.z);
                float f2 = fmaf(cA1.y, xr[2], cA1.x);
                float f3 = fmaf(cA1.w, xr[3], cA1.z);
                float f4 = fmaf(cA2.y, xr[4], cA2.x);
                float f5 = fmaf(cA2.w, xr[5], cA2.z);
                float f6 = fmaf(cA3.y, xr[6], cA3.x);
                float f7 = fmaf(cA3.w, xr[7], cA3.z);
                acc[r] *= ((f0 * f1) * (f2 * f3)) * ((f4 * f5) * (f6 * f7));
            }
            // Prefetch ab for stage st+2 (wrap: last-iter loads dead but
            // in-bounds). Issued after compute so the stage-A vmcnt wait
            // next iteration only drains this batch.
            int np = ((st + 2) & (N_ST - 1)) * 4;
            cA0 = abp[np + 0]; cA1 = abp[np + 1];
            cA2 = abp[np + 2]; cA3 = abp[np + 3];
        }
        // ---- stage B: i-block st+1, x slab xs[64..127] ----
        {
#pragma unroll
            for (int r = 0; r < R_ROWS; ++r) {
                const float* xr = xs + 64 + r * 8;
                float f0 = fmaf(cB0.y, xr[0], cB0.x);
                float f1 = fmaf(cB0.w, xr[1], cB0.z);
                float f2 = fmaf(cB1.y, xr[2], cB1.x);
                float f3 = fmaf(cB1.w, xr[3], cB1.z);
                float f4 = fmaf(cB2.y, xr[4], cB2.x);
                float f5 = fmaf(cB2.w, xr[5], cB2.z);
                float f6 = fmaf(cB3.y, xr[6], cB3.x);
                float f7 = fmaf(cB3.w, xr[7], cB3.z);
                acc[r] *= ((f0 * f1) * (f2 * f3)) * ((f4 * f5) * (f6 * f7));
            }
            int np = ((st + 3) & (N_ST - 1)) * 4;
            cB0 = abp[np + 0]; cB1 = abp[np + 1];
            cB2 = abp[np + 2]; cB3 = abp[np + 3];
        }
        xs += 128;                            // uniform scalar bump (2 slabs)
    }

    // Combine 4 i-chunk partials per (row, o) via LDS, stride-1 conflict-free.
#pragma unroll
    for (int r = 0; r < R_ROWS; ++r)
        part[y][r][o_l] = acc[r];
    __syncthreads();
#pragma unroll
    for (int rr = 0; rr < R_ROWS / W_CHUNK; ++rr) {  // 2 rows per y-group
        int r = y * (R_ROWS / W_CHUNK) + rr;
        float v = part[0][r][o_l] * part[1][r][o_l]
                * part[2][r][o_l] * part[3][r][o_l];
        out[(size_t)(b0 + r) * O_DIM + o] = v;
    }
}

extern "C" void kernel_launch(void* const* d_in, const int* in_sizes, int n_in,
                              void* d_out, int out_size, void* d_ws, size_t ws_size,
                              hipStream_t stream) {
    const float* x        = (const float*)d_in[0];   // (B, I) fp32
    const float* w_logits = (const float*)d_in[1];   // (I, O) fp32
    const float* s_logits = (const float*)d_in[2];   // (I, O) fp32
    float* out = (float*)d_out;                      // (B, O) fp32
    float4* abT = (float4*)((char*)d_ws + ABT_OFFSET);   // [0, 2MB)
    float*  xt  = (float*)((char*)d_ws + XT_OFFSET);     // [2MB, 6MB)

    // Fused setup: 512 abT-blocks + 1024 x-retile blocks.
    setup_kernel<<<dim3(1536), dim3(256), 0, stream>>>(
        x, w_logits, s_logits, abT, xt);

    // Grid (O/256, B/8) = (2, 256) = 512 blocks of (256,4)=1024 threads.
    fuzzy_main<<<dim3(O_DIM / 256, B_DIM / R_ROWS), dim3(256, W_CHUNK), 0, stream>>>(
        abT, xt, out);
}

// Round 9
// 113.843 us; speedup vs baseline: 3.3443x; 3.3443x over previous
//
#include <hip/hip_runtime.h>
#include <hip/hip_bf16.h>
#include <math.h>

// Problem constants (from reference): B=2048, I=512, O=512
#define B_DIM 2048
#define I_DIM 512
#define O_DIM 512

constexpr int R_ROWS = 16;   // b-rows per block (ab L1 traffic = 256 blocks' worth = 256MB)
constexpr int YC     = 8;    // i-chunks per block (threadIdx.y), 64 i each
constexpr int OL     = 128;  // o-lanes per block
constexpr int N_ST   = 16;   // 4-i stages per chunk (64 i / 4)

// ws layout: abT [0, 2MB), xt [2MB, 6MB).
//   abT: float4 (a0,b0,a1,b1) at abT[o*256 + p], p = i/2 — per-o column 4KB
//        contiguous; chunk y starts at pair y*32; stage offsets immediate.
//   xt : per (g,y,st) slab of 16 rows x 4 i = 64 floats = 256B contiguous:
//        xt4[((g*8+y)*16+st)*16 + r] = x[g*16+r][(y*16+st)*4 .. +3]
//        -> one stage's x = 4 merged s_load_dwordx16 (64 SGPRs, fits).
#define ABT_OFFSET 0
#define XT_OFFSET ((size_t)2 * 1024 * 1024)

// ---------------------------------------------------------------------------
// Setup: blocks [0,512) build abT, blocks [512,1536) re-tile x.
//   factor[b,i,o] = a[i,o] + bcoef[i,o]*x[b,i];  a = 1-w*s, b = w*(2s-1)
// ---------------------------------------------------------------------------
__global__ __launch_bounds__(256) void setup_kernel(
    const float* __restrict__ x,
    const float* __restrict__ w_logits,
    const float* __restrict__ s_logits,
    float4* __restrict__ abT,
    float4* __restrict__ xt4)
{
    const int blk = blockIdx.x;
    if (blk < 512) {
        int t = blk * 256 + threadIdx.x;          // 0..131071
        int o = t & (O_DIM - 1);                  // lane-fast -> coalesced reads
        int p = t >> 9;                           // i-pair, 0..255
        int i0 = 2 * p;

        float zw0 = w_logits[(i0 + 0) * O_DIM + o];
        float zs0 = s_logits[(i0 + 0) * O_DIM + o];
        float zw1 = w_logits[(i0 + 1) * O_DIM + o];
        float zs1 = s_logits[(i0 + 1) * O_DIM + o];

        float w0 = 1.0f / (1.0f + expf(-zw0));
        float s0 = 1.0f / (1.0f + expf(-zs0));
        float w1 = 1.0f / (1.0f + expf(-zw1));
        float s1 = 1.0f / (1.0f + expf(-zs1));

        float4 v;
        v.x = fmaf(-w0, s0, 1.0f);        // a0
        v.y = w0 * (2.0f * s0 - 1.0f);    // b0
        v.z = fmaf(-w1, s1, 1.0f);        // a1
        v.w = w1 * (2.0f * s1 - 1.0f);    // b1
        abT[(size_t)o * 256 + p] = v;     // scattered 16B store (2MB total)
    } else {
        int t  = (blk - 512) * 256 + threadIdx.x; // 0..262143
        int iq = t & 127;                         // i-quad, lane-fast read
        int b  = t >> 7;
        float4 v = ((const float4*)x)[(size_t)b * 128 + iq];
        int g = b >> 4, r = b & 15;               // b-group, row
        int y = iq >> 4, st = iq & 15;            // chunk, stage
        xt4[(size_t)((g * 8 + y) * 16 + st) * 16 + r] = v;
    }
}

// ---------------------------------------------------------------------------
// Main. Block (128, 8) = 1024 thr = 16 waves: 128 o-lanes x 8 i-chunks (64 i
// each; each wave has uniform y). Grid (4, 128) = 512 blocks -> 2 blocks/CU
// = 32 waves/CU = 8 waves/SIMD.
// WHY THIS SHAPE (R3-R8 synthesis): all prior variants plateaued at ~40us
// because EITHER ab L1 traffic hit the ~64 B/cyc/CU L1 ceiling (R=8: 512MB)
// OR wave count was 4/SIMD (latency-exposed s_load drains). This is the
// first config with BOTH R=16 (ab L1 = 256MB ~ half ceiling) AND 8
// waves/SIMD (drain 400cyc per 256cyc math x 8 waves = 3.1x issue margin).
// Register feasibility (R8 spill lesson): x batch 64 SGPR + ~24 sys/addr
// < 102; VGPR ~46 < 64 cap at 8 waves/EU.
// ---------------------------------------------------------------------------
__global__ __launch_bounds__(1024, 8) void fuzzy_main(
    const float4* __restrict__ abT,
    const float4* __restrict__ xt4,
    float* __restrict__ out)
{
    __shared__ float part[YC][R_ROWS][OL];    // 64 KB (2 blocks/CU = 128 <= 160)

    const int o_l = threadIdx.x;              // 0..127
    const int y   = __builtin_amdgcn_readfirstlane((int)threadIdx.y); // 0..7
    const int o   = blockIdx.x * OL + o_l;
    const int g   = blockIdx.y;               // b-group (16 rows)
    const int b0  = g * R_ROWS;

    // ab column for this (o, y): pairs [y*32, y*32+32); stage st uses float4s
    // [2st, 2st+1] at byte offsets 32st (+16) <= 496+16 — immediates.
    const float4* __restrict__ abY = abT + (size_t)o * 256 + y * 32;
    // x slabs for this (g, y): 16 stages x 16 float4, contiguous, uniform.
    const float4* __restrict__ xq  = xt4 + (size_t)(g * 8 + y) * 256;

    float acc[R_ROWS];
#pragma unroll
    for (int r = 0; r < R_ROWS; ++r) acc[r] = 1.0f;

    // ab prefetch depth 1 (in flight one full stage ~650cyc >= L2 latency).
    float4 pa = abY[0];
    float4 pb = abY[1];

    for (int st = 0; st < N_ST; ++st) {
        // Stage x batch: 16 uniform float4 -> 4 merged s_load_dwordx16 into
        // SGPRs; one lgkmcnt drain per 256 cyc of math.
        float4 xv[16];
#pragma unroll
        for (int r = 0; r < 16; ++r) xv[r] = xq[st * 16 + r];

        float4 c0 = pa, c1 = pb;              // (a0,b0,a1,b1) for i0,i1 / i2,i3
        // Prefetch next stage. On the last stage this overruns abT by <=32B
        // into xt (dead value, in-bounds of ws).
        pa = abY[2 * st + 2];
        pb = abY[2 * st + 3];

#pragma unroll
        for (int r = 0; r < R_ROWS; ++r) {
            float f0 = fmaf(c0.y, xv[r].x, c0.x);
            float f1 = fmaf(c0.w, xv[r].y, c0.z);
            float f2 = fmaf(c1.y, xv[r].z, c1.x);
            float f3 = fmaf(c1.w, xv[r].w, c1.z);
            acc[r] *= (f0 * f1) * (f2 * f3);
        }
    }

    // Combine 8 i-chunk partials per (row, o) via LDS.
#pragma unroll
    for (int r = 0; r < R_ROWS; ++r)
        part[y][r][o_l] = acc[r];
    __syncthreads();
    // 2048 outputs (16 r x 128 o), 1024 threads -> 2 each; stride-1 in o
    // across lanes (conflict-free reads, coalesced 512B stores).
    const int tid = y * OL + o_l;
#pragma unroll
    for (int h = 0; h < 2; ++h) {
        int idx = tid + h * 1024;
        int r   = idx >> 7;                   // 0..15
        int oe  = idx & 127;
        float v = ((part[0][r][oe] * part[1][r][oe])
                 * (part[2][r][oe] * part[3][r][oe]))
                * ((part[4][r][oe] * part[5][r][oe])
                 * (part[6][r][oe] * part[7][r][oe]));
        out[(size_t)(b0 + r) * O_DIM + blockIdx.x * OL + oe] = v;
    }
}

extern "C" void kernel_launch(void* const* d_in, const int* in_sizes, int n_in,
                              void* d_out, int out_size, void* d_ws, size_t ws_size,
                              hipStream_t stream) {
    const float* x        = (const float*)d_in[0];   // (B, I) fp32
    const float* w_logits = (const float*)d_in[1];   // (I, O) fp32
    const float* s_logits = (const float*)d_in[2];   // (I, O) fp32
    float* out = (float*)d_out;                      // (B, O) fp32
    float4* abT = (float4*)((char*)d_ws + ABT_OFFSET);   // [0, 2MB)
    float4* xt4 = (float4*)((char*)d_ws + XT_OFFSET);    // [2MB, 6MB)

    // Fused setup: 512 abT-blocks + 1024 x-retile blocks.
    setup_kernel<<<dim3(1536), dim3(256), 0, stream>>>(
        x, w_logits, s_logits, abT, xt4);

    // Grid (O/128, B/16) = (4, 128) = 512 blocks of (128,8)=1024 threads.
    fuzzy_main<<<dim3(O_DIM / OL, B_DIM / R_ROWS), dim3(OL, YC), 0, stream>>>(
        abT, xt4, out);
}

// Round 10
// 112.898 us; speedup vs baseline: 3.3723x; 1.0084x over previous
//
#include <hip/hip_runtime.h>
#include <hip/hip_bf16.h>
#include <math.h>

// Problem constants (from reference): B=2048, I=512, O=512
#define B_DIM 2048
#define I_DIM 512
#define O_DIM 512

constexpr int R_ROWS  = 8;    // b-rows per block
constexpr int W_CHUNK = 4;    // i-chunks (threadIdx.y), 128 i each
constexpr int N_ST    = 32;   // 4-i stages per chunk

// ws layout: abL [0, 2MB), xt [2MB, 6MB); overruns land in ws slack.
//   abL: float4 (a0,b0,a1,b1) at abL[p*O_DIM + o], p = i/2 — LANE-FAST in o
//        (R9's o-major layout made every ab load a 4KB-stride 64-txn gather;
//        this restores 1KB coalesced lines).
//   xt : slab per (g,y,st): 8 rows x 4 i = 128B contiguous:
//        xt4[((g*4+y)*32+st)*8 + r] = x[g*8+r][y*128+st*4 .. +3]
//        -> one stage's x batch = 2 merged s_load_dwordx16 (32 SGPRs).
#define ABL_OFFSET 0
#define XT_OFFSET ((size_t)2 * 1024 * 1024)

// ---------------------------------------------------------------------------
// Setup: blocks [0,512) build abL, blocks [512,1536) re-tile x.
//   factor[b,i,o] = a[i,o] + bcoef[i,o]*x[b,i];  a = 1-w*s, b = w*(2s-1)
// ---------------------------------------------------------------------------
__global__ __launch_bounds__(256) void setup_kernel(
    const float* __restrict__ x,
    const float* __restrict__ w_logits,
    const float* __restrict__ s_logits,
    float4* __restrict__ abL,
    float4* __restrict__ xt4)
{
    const int blk = blockIdx.x;
    if (blk < 512) {
        int t = blk * 256 + threadIdx.x;          // 0..131071
        int o = t & (O_DIM - 1);                  // lane-fast
        int p = t >> 9;                           // i-pair, 0..255
        int i0 = 2 * p;

        float zw0 = w_logits[(i0 + 0) * O_DIM + o];
        float zs0 = s_logits[(i0 + 0) * O_DIM + o];
        float zw1 = w_logits[(i0 + 1) * O_DIM + o];
        float zs1 = s_logits[(i0 + 1) * O_DIM + o];

        float w0 = 1.0f / (1.0f + expf(-zw0));
        float s0 = 1.0f / (1.0f + expf(-zs0));
        float w1 = 1.0f / (1.0f + expf(-zw1));
        float s1 = 1.0f / (1.0f + expf(-zs1));

        float4 v;
        v.x = fmaf(-w0, s0, 1.0f);        // a0
        v.y = w0 * (2.0f * s0 - 1.0f);    // b0
        v.z = fmaf(-w1, s1, 1.0f);        // a1
        v.w = w1 * (2.0f * s1 - 1.0f);    // b1
        abL[(size_t)p * O_DIM + o] = v;   // coalesced 16B store
    } else {
        int t  = (blk - 512) * 256 + threadIdx.x; // 0..262143
        int iq = t & 127;                         // i-quad, lane-fast read
        int b  = t >> 7;
        float4 v = ((const float4*)x)[(size_t)b * 128 + iq];
        int g = b >> 3, r = b & 7;                // b-group, row
        int y = iq >> 5, st = iq & 31;            // chunk, stage
        xt4[(size_t)(((g * 4 + y) * 32 + st) * 8) + r] = v;
    }
}

// ---------------------------------------------------------------------------
// Main. Block (256,4) = 16 waves, lanes = o, y = i-chunk (wave-uniform).
// Grid (2,256) = 512 blocks -> 2 blocks/CU, 8 waves/SIMD.
// R5's proven structure (x: SGPR double-buffer via merged s_load_dwordx16;
// ab: lane-fast coalesced VMEM) + R9's address economy (running pointer
// bumps only — R5/R6 lost ~40% busy-time to in-loop 64-bit address muls)
// + 4-deep ab buffer (prefetch distance 4 stages ~= 512 cyc >= L2 latency),
// zero rotation copies (each buffer refilled after its consuming stage).
// ---------------------------------------------------------------------------
__global__ __launch_bounds__(1024, 8) void fuzzy_main(
    const float4* __restrict__ abL,
    const float4* __restrict__ xt4,
    float* __restrict__ out)
{
    __shared__ float part[W_CHUNK][R_ROWS][256];   // 32 KB (2 blocks/CU)

    const int o_l = threadIdx.x;              // 0..255
    const int o   = blockIdx.x * 256 + o_l;
    const int y   = __builtin_amdgcn_readfirstlane((int)threadIdx.y); // 0..3
    const int g   = blockIdx.y;               // b-group (8 rows)
    const int b0  = g * R_ROWS;

    // ab: chunk y covers p-rows [y*64, y*64+64); stage uses rows 2st, 2st+1.
    const float4* __restrict__ abp = abL + (size_t)(y * 64) * O_DIM + o;
    // x: 32 slabs of 8 float4, contiguous per (g,y); wave-uniform pointer.
    const float4* __restrict__ xq  = xt4 + (size_t)(g * W_CHUNK + y) * (N_ST * R_ROWS);

    float acc[R_ROWS];
#pragma unroll
    for (int r = 0; r < R_ROWS; ++r) acc[r] = 1.0f;

    // ab quad-buffer preload: buffer J holds stage (st+J)'s two p-rows.
    float4 cA0 = abp[0 * O_DIM], cA1 = abp[1 * O_DIM];
    float4 cB0 = abp[2 * O_DIM], cB1 = abp[3 * O_DIM];
    float4 cC0 = abp[4 * O_DIM], cC1 = abp[5 * O_DIM];
    float4 cD0 = abp[6 * O_DIM], cD1 = abp[7 * O_DIM];

    // x double-buffer preload (stage parity): 2 merged s_load_dwordx16 each.
    float4 xA[R_ROWS], xB[R_ROWS];
#pragma unroll
    for (int r = 0; r < R_ROWS; ++r) xA[r] = xq[r];
#pragma unroll
    for (int r = 0; r < R_ROWS; ++r) xB[r] = xq[R_ROWS + r];

    // Running refill pointers (SALU bumps only — no in-loop index math).
    const float4* pf = abp + 8 * O_DIM;       // next ab p-row to fetch
    const float4* xf = xq + 2 * R_ROWS;       // next x slab to fetch

#define STAGE(C0, C1, XS)                                         \
    {                                                             \
        _Pragma("unroll")                                         \
        for (int r = 0; r < R_ROWS; ++r) {                        \
            float f0 = fmaf(C0.y, XS[r].x, C0.x);                 \
            float f1 = fmaf(C0.w, XS[r].y, C0.z);                 \
            float f2 = fmaf(C1.y, XS[r].z, C1.x);                 \
            float f3 = fmaf(C1.w, XS[r].w, C1.z);                 \
            acc[r] *= (f0 * f1) * (f2 * f3);                      \
        }                                                         \
        C0 = pf[0]; C1 = pf[O_DIM]; pf += 2 * O_DIM;              \
    }
#define XREFILL(XS)                                               \
    {                                                             \
        _Pragma("unroll")                                         \
        for (int r = 0; r < R_ROWS; ++r) XS[r] = xf[r];           \
        xf += R_ROWS;                                             \
    }

    for (int it = 0; it < N_ST / 4; ++it) {   // 8 iterations, 4 stages each
        STAGE(cA0, cA1, xA) XREFILL(xA)       // stage 4it   (refill->4it+2)
        STAGE(cB0, cB1, xB) XREFILL(xB)       // stage 4it+1 (refill->4it+3)
        STAGE(cC0, cC1, xA) XREFILL(xA)       // stage 4it+2 (refill->4it+4)
        STAGE(cD0, cD1, xB) XREFILL(xB)       // stage 4it+3 (refill->4it+5)
        // ab refills (inside STAGE) target stage+4; final-iter overruns land
        // <=70KB past abL (into xt, dead values); x overrun <=256B past xt
        // (into ws slack). Both in-bounds of the 256MB ws.
    }
#undef STAGE
#undef XREFILL

    // Combine 4 i-chunk partials per (row, o) via LDS, stride-1 conflict-free.
#pragma unroll
    for (int r = 0; r < R_ROWS; ++r)
        part[y][r][o_l] = acc[r];
    __syncthreads();
#pragma unroll
    for (int rr = 0; rr < R_ROWS / W_CHUNK; ++rr) {  // 2 rows per y-group
        int r = y * (R_ROWS / W_CHUNK) + rr;
        float v = part[0][r][o_l] * part[1][r][o_l]
                * part[2][r][o_l] * part[3][r][o_l];
        out[(size_t)(b0 + r) * O_DIM + o] = v;
    }
}

extern "C" void kernel_launch(void* const* d_in, const int* in_sizes, int n_in,
                              void* d_out, int out_size, void* d_ws, size_t ws_size,
                              hipStream_t stream) {
    const float* x        = (const float*)d_in[0];   // (B, I) fp32
    const float* w_logits = (const float*)d_in[1];   // (I, O) fp32
    const float* s_logits = (const float*)d_in[2];   // (I, O) fp32
    float* out = (float*)d_out;                      // (B, O) fp32
    float4* abL = (float4*)((char*)d_ws + ABL_OFFSET);   // [0, 2MB)
    float4* xt4 = (float4*)((char*)d_ws + XT_OFFSET);    // [2MB, 6MB)

    // Fused setup: 512 abL-blocks + 1024 x-retile blocks.
    setup_kernel<<<dim3(1536), dim3(256), 0, stream>>>(
        x, w_logits, s_logits, abL, xt4);

    // Grid (O/256, B/8) = (2, 256) = 512 blocks of (256,4)=1024 threads.
    fuzzy_main<<<dim3(O_DIM / 256, B_DIM / R_ROWS), dim3(256, W_CHUNK), 0, stream>>>(
        abL, xt4, out);
}